// Round 1
// 376.631 us; speedup vs baseline: 1.0399x; 1.0399x over previous
//
#include <hip/hip_runtime.h>
#include <cstdint>

// Problem constants (fixed instance: B=8192, Cin=4096, Cout=1024, T=10)
#define B_DIM 8192
#define CIN   4096
#define COUT  1024
#define NPLN  3072   // 3 digit planes stacked along N

// Fixed-point quantization of W: 23-bit minus headroom so top balanced digit <= 127.
constexpr double W_SCALE   = 83230720.0;        // (2^23 - 2^16) / 0.1
constexpr int    QMAX      = 8323072;           // 2^23 - 2^16
constexpr double INV_SCALE = 0.1 / 8323072.0;   // 1 / W_SCALE

using i32x4 = __attribute__((ext_vector_type(4))) int;

// ---- async global->LDS, 16B per lane. LDS dest is wave-uniform base + lane*16.
__device__ __forceinline__ void async_copy16(void* lds, const void* g) {
    auto l = (__attribute__((address_space(3))) void*)(uintptr_t)(lds);
    auto p = (const __attribute__((address_space(1))) void*)(uintptr_t)(g);
    __builtin_amdgcn_global_load_lds(p, l, 16, 0, 0);
}

// ---------------------------------------------------------------------------
// Kernel 1: x (fp32 0/1) -> i8. 16 elements per thread.
__global__ void prep_x(const float* __restrict__ x, int8_t* __restrict__ Ai) {
    const int idx = blockIdx.x * 256 + threadIdx.x;      // 2,097,152 threads
    const float4* xp = (const float4*)x + (size_t)idx * 4;
    float4 v0 = xp[0], v1 = xp[1], v2 = xp[2], v3 = xp[3];
    auto pk = [](float a, float b, float c, float d) -> int {
        return (a != 0.f ? 1 : 0) | ((b != 0.f ? 1 : 0) << 8) |
               ((c != 0.f ? 1 : 0) << 16) | ((d != 0.f ? 1 : 0) << 24);
    };
    int4 r;
    r.x = pk(v0.x, v0.y, v0.z, v0.w);
    r.y = pk(v1.x, v1.y, v1.z, v1.w);
    r.z = pk(v2.x, v2.y, v2.z, v2.w);
    r.w = pk(v3.x, v3.y, v3.z, v3.w);
    ((int4*)Ai)[idx] = r;
}

// ---------------------------------------------------------------------------
// Kernel 2: W (fp32) -> 3 balanced base-256 digit planes (i8), stacked N-major.
__global__ void prep_w(const float* __restrict__ W, int8_t* __restrict__ Bd,
                       unsigned long long* __restrict__ cm) {
    const int idx = blockIdx.x * 256 + threadIdx.x;      // 1,048,576 threads, 4 elems each
    float4 w = ((const float4*)W)[idx];
    float ws[4] = {w.x, w.y, w.z, w.w};
    char dg[3][4];
#pragma unroll
    for (int k = 0; k < 4; ++k) {
        int qv = __double2int_rn((double)ws[k] * W_SCALE);
        qv = max(0, min(QMAX, qv));
        int d0 = ((qv + 128) & 255) - 128; int tq = (qv - d0) >> 8;
        int d1 = ((tq + 128) & 255) - 128; int d2 = (tq - d1) >> 8;   // d2 in [0,127]
        dg[0][k] = (char)d0; dg[1][k] = (char)d1; dg[2][k] = (char)d2;
    }
    const size_t off = (size_t)idx * 4;  // = j*4096 + c (no row crossing: 4096 % 4 == 0)
#pragma unroll
    for (int p = 0; p < 3; ++p) {
        char4 c4; c4.x = dg[p][0]; c4.y = dg[p][1]; c4.z = dg[p][2]; c4.w = dg[p][3];
        *(char4*)(Bd + (size_t)p * COUT * CIN + off) = c4;
    }
    if (idx < COUT) cm[idx] = 0ull;
}

// ---------------------------------------------------------------------------
// Kernel 3: i8 GEMM  S[8192][3072] = Ai[8192][4096] * Bd[3072][4096]^T  (i32 exact)
// 256x256 tile, BK=128 i8, 8 waves (2Mx4N), 8-phase schedule per 2 K-tiles:
// per phase {ds_read frags | 1 half-tile global_load_lds | bar | lgkm0 |
// setprio(1) 16xMFMA setprio(0) | vmcnt(8) | bar}. Raw s_barrier (no vmcnt
// drain), counted vmcnt keeps 4 half-stages (8 loads) in flight across tile
// boundaries. LDS XOR-swizzle chunk^(row&7) applied on BOTH the pre-swizzled
// global staging source and the ds_read address (linear global_load_lds dest).
template <int MH, int NH>
__device__ __forceinline__ void mma_quad(const i32x4 (&a)[4][2], const i32x4 (&b)[2][2],
                                         i32x4 (&acc)[2][2][4][2]) {
    __builtin_amdgcn_s_setprio(1);
#pragma unroll
    for (int mi = 0; mi < 4; ++mi)
#pragma unroll
        for (int ni = 0; ni < 2; ++ni)
#pragma unroll
            for (int kk = 0; kk < 2; ++kk)
                acc[MH][NH][mi][ni] = __builtin_amdgcn_mfma_i32_16x16x64_i8(
                    a[mi][kk], b[ni][kk], acc[MH][NH][mi][ni], 0, 0, 0);
    __builtin_amdgcn_s_setprio(0);
}

#define BAR()   __builtin_amdgcn_s_barrier()
#define LGKM0() asm volatile("s_waitcnt lgkmcnt(0)" ::: "memory")
#define VMW(n)  asm volatile("s_waitcnt vmcnt(" #n ")" ::: "memory")

__global__ __launch_bounds__(512, 2) void gemm_i8(const int8_t* __restrict__ A,
                                                  const int8_t* __restrict__ Bm,
                                                  int* __restrict__ S) {
    // [0,65536) = A tiles (2 bufs x 256 x 128B), [65536,131072) = B tiles
    __shared__ alignas(16) int8_t lds[131072];
    const int tid  = threadIdx.x;
    const int lane = tid & 63;
    const int wave = tid >> 6;

    // XCD-aware bijective swizzle: 384 blocks = 8 XCDs x 48; bm-major in chunk
    const int wg = ((int)blockIdx.x & 7) * 48 + ((int)blockIdx.x >> 3);
    const int bm = wg & 31;          // 0..31  M tiles
    const int bn = wg >> 5;          // 0..11  N tiles

    // ---- staging constants: thread t owns LDS slot (row tid>>3, chunk tid&7),
    // fetches pre-swizzled global chunk (tid&7) ^ (row&7).
    const int stid   = tid >> 3;                            // 0..63
    const int cswz16 = ((tid & 7) ^ (stid & 7)) << 4;
    const int8_t* gA = A  + (size_t)(bm * 256 + stid) * CIN + cswz16;
    const int8_t* gB = Bm + (size_t)(bn * 256 + stid) * CIN + cswz16;
    const int wv1024 = wave << 10;

#define STAGE_A(t_, hs_) do {                                                   \
    int8_t* d_ = lds + (((t_) & 1) << 15) + ((hs_) << 14) + wv1024;             \
    const int8_t* s_ = gA + (size_t)((hs_) * 128) * CIN + ((t_) << 7);          \
    async_copy16(d_,        s_);                                                \
    async_copy16(d_ + 8192, s_ + (size_t)64 * CIN);                             \
} while (0)
#define STAGE_B(t_, hs_) do {                                                   \
    int8_t* d_ = lds + 65536 + (((t_) & 1) << 15) + ((hs_) << 14) + wv1024;     \
    const int8_t* s_ = gB + (size_t)((hs_) * 128) * CIN + ((t_) << 7);          \
    async_copy16(d_,        s_);                                                \
    async_copy16(d_ + 8192, s_ + (size_t)64 * CIN);                             \
} while (0)

    // ---- fragment addressing (16x16x64: lane holds [m=lane&15][16B at (lane>>4)*16])
    const int wr = wave >> 2, wc = wave & 3;
    const int fr = lane & 15;
    const int q  = lane >> 4;
    const int ck0 = (q ^ (lane & 7)) << 4;   // swizzled k-chunk 0; k-chunk 1 = ^64
    const int ck1 = ck0 ^ 64;
    const int abase = (wr * 64 + fr) * 128;           // + mh*16384 + mi*2048 + buf*32768
    const int bbase = 65536 + (wc * 32 + fr) * 128;   // + nh*16384 + ni*2048 + buf*32768

    i32x4 a[4][2], b0[2][2], b1[2][2];
    i32x4 acc[2][2][4][2] = {};

#define LDA(buf_, mh_) do {                                                     \
    const int8_t* p_ = lds + ((buf_) << 15) + ((mh_) << 14) + abase;            \
    a[0][0] = *(const i32x4*)(p_ + ck0);        a[0][1] = *(const i32x4*)(p_ + ck1);        \
    a[1][0] = *(const i32x4*)(p_ + 2048 + ck0); a[1][1] = *(const i32x4*)(p_ + 2048 + ck1); \
    a[2][0] = *(const i32x4*)(p_ + 4096 + ck0); a[2][1] = *(const i32x4*)(p_ + 4096 + ck1); \
    a[3][0] = *(const i32x4*)(p_ + 6144 + ck0); a[3][1] = *(const i32x4*)(p_ + 6144 + ck1); \
} while (0)
#define LDB(arr_, buf_, nh_) do {                                               \
    const int8_t* p_ = lds + ((buf_) << 15) + ((nh_) << 14) + bbase;            \
    arr_[0][0] = *(const i32x4*)(p_ + ck0);        arr_[0][1] = *(const i32x4*)(p_ + ck1);        \
    arr_[1][0] = *(const i32x4*)(p_ + 2048 + ck0); arr_[1][1] = *(const i32x4*)(p_ + 2048 + ck1); \
} while (0)

    // prologue: stream order per tile is [Ah0, Bh0, Bh1, Ah1]; issue 6 stages
    STAGE_A(0, 0); STAGE_B(0, 0); STAGE_B(0, 1); STAGE_A(0, 1);
    STAGE_A(1, 0); STAGE_B(1, 0);
    VMW(8); BAR();    // oldest 4 loads (A0h0,B0h0) landed

#pragma unroll 1
    for (int it = 0; it < 15; ++it) {
        const int t = it * 2;
        // ---- tile t (buf 0): phases (mh,nh) = 00,01,10,11 ----
        LDA(0, 0); LDB(b0, 0, 0); STAGE_B(t + 1, 1); BAR(); LGKM0(); mma_quad<0, 0>(a, b0, acc); VMW(8); BAR();
        LDB(b1, 0, 1);            STAGE_A(t + 1, 1); BAR(); LGKM0(); mma_quad<0, 1>(a, b1, acc); VMW(8); BAR();
        LDA(0, 1);                STAGE_A(t + 2, 0); BAR(); LGKM0(); mma_quad<1, 0>(a, b0, acc); VMW(8); BAR();
                                  STAGE_B(t + 2, 0); BAR(); LGKM0(); mma_quad<1, 1>(a, b1, acc); VMW(8); BAR();
        // ---- tile t+1 (buf 1) ----
        LDA(1, 0); LDB(b0, 1, 0); STAGE_B(t + 2, 1); BAR(); LGKM0(); mma_quad<0, 0>(a, b0, acc); VMW(8); BAR();
        LDB(b1, 1, 1);            STAGE_A(t + 2, 1); BAR(); LGKM0(); mma_quad<0, 1>(a, b1, acc); VMW(8); BAR();
        LDA(1, 1);                STAGE_A(t + 3, 0); BAR(); LGKM0(); mma_quad<1, 0>(a, b0, acc); VMW(8); BAR();
                                  STAGE_B(t + 3, 0); BAR(); LGKM0(); mma_quad<1, 1>(a, b1, acc); VMW(8); BAR();
    }
    // ---- tail: tiles 30 (buf 0) and 31 (buf 1), waits relax 8 -> 4 -> 2 -> 0
    LDA(0, 0); LDB(b0, 0, 0); STAGE_B(31, 1); BAR(); LGKM0(); mma_quad<0, 0>(a, b0, acc); VMW(8); BAR();
    LDB(b1, 0, 1);            STAGE_A(31, 1); BAR(); LGKM0(); mma_quad<0, 1>(a, b1, acc); VMW(8); BAR();
    LDA(0, 1);                                BAR(); LGKM0(); mma_quad<1, 0>(a, b0, acc); VMW(8); BAR();
                                              BAR(); LGKM0(); mma_quad<1, 1>(a, b1, acc); VMW(4); BAR();
    LDA(1, 0); LDB(b0, 1, 0);                 BAR(); LGKM0(); mma_quad<0, 0>(a, b0, acc); VMW(2); BAR();
    LDB(b1, 1, 1);                            BAR(); LGKM0(); mma_quad<0, 1>(a, b1, acc); VMW(0); BAR();
    LDA(1, 1);                                BAR(); LGKM0(); mma_quad<1, 0>(a, b0, acc);
                                                              mma_quad<1, 1>(a, b1, acc);

    // epilogue: C/D layout col = lane&15 (N), row = (lane>>4)*4 + reg (M)
    const int gm0 = bm * 256 + wr * 64 + q * 4;
    const int gn0 = bn * 256 + wc * 32 + fr;
#pragma unroll
    for (int mh = 0; mh < 2; ++mh)
#pragma unroll
        for (int nh = 0; nh < 2; ++nh)
#pragma unroll
            for (int mi = 0; mi < 4; ++mi)
#pragma unroll
                for (int ni = 0; ni < 2; ++ni) {
                    const int gn = gn0 + nh * 128 + ni * 16;
#pragma unroll
                    for (int reg = 0; reg < 4; ++reg) {
                        const int gm = gm0 + mh * 128 + mi * 16 + reg;
                        S[(size_t)gm * NPLN + gn] = acc[mh][nh][mi][ni][reg];
                    }
                }
#undef STAGE_A
#undef STAGE_B
#undef LDA
#undef LDB
}

// ---------------------------------------------------------------------------
// Kernel 4: column max of i (fp64) via monotone-bits atomicMax (i >= 0).
__global__ void colmax_k(const int* __restrict__ S, unsigned long long* __restrict__ cm) {
    const int j = blockIdx.x * 256 + threadIdx.x;
    const int rbeg = blockIdx.y * 128;
    double m = 0.0;
    for (int r = rbeg; r < rbeg + 128; ++r) {
        const int* row = S + (size_t)r * NPLN;
        long long s0 = row[j], s1 = row[COUT + j], s2 = row[2 * COUT + j];
        long long isum = s0 + s1 * 256 + s2 * 65536;
        double v = (double)isum * INV_SCALE;
        m = fmax(m, v);
    }
    atomicMax(cm + j, (unsigned long long)__double_as_longlong(m));
}

// ---------------------------------------------------------------------------
// Kernel 5: LIF/WTA scan, one wave per batch row, 16 fp64 neurons per lane.
__global__ void scan_k(const int* __restrict__ S, const unsigned long long* __restrict__ cm,
                       const int* __restrict__ twp, float* __restrict__ out) {
    const int lane = threadIdx.x & 63;
    const int wave = threadIdx.x >> 6;
    const int b = blockIdx.x * 4 + wave;
    const int T = *twp;
    const int* row = S + (size_t)b * NPLN;

    double iv[16], mem[16], thr[16];
    int cnt[16];
    double imax = 0.0;
#pragma unroll
    for (int u = 0; u < 16; ++u) {
        const int j = lane + u * 64;
        long long s0 = row[j], s1 = row[COUT + j], s2 = row[2 * COUT + j];
        long long isum = s0 + s1 * 256 + s2 * 65536;
        iv[u]  = (double)isum * INV_SCALE;
        thr[u] = 3.0 * __longlong_as_double((long long)cm[j]);
        mem[u] = 0.0; cnt[u] = 0;
        imax = fmax(imax, iv[u]);
    }
#pragma unroll
    for (int d = 32; d >= 1; d >>= 1) imax = fmax(imax, __shfl_xor(imax, d, 64));
    const double h = 1.625 * imax;

    for (int t = 0; t < T; ++t) {
        int first = 0x7fffffff;
        bool sp[16];
#pragma unroll
        for (int u = 0; u < 16; ++u) {
            mem[u] = mem[u] * 0.99 + iv[u];
            sp[u] = mem[u] > thr[u];
            if (sp[u]) first = min(first, lane + u * 64);
        }
#pragma unroll
        for (int d = 32; d >= 1; d >>= 1) first = min(first, __shfl_xor(first, d, 64));
        const bool rowspike = first < 0x7fffffff;
#pragma unroll
        for (int u = 0; u < 16; ++u) {
            if (sp[u]) mem[u] = 0.0;
            if (rowspike) {
                if (lane + u * 64 == first) cnt[u]++;
                else mem[u] -= h;
            }
        }
    }
#pragma unroll
    for (int u = 0; u < 16; ++u)
        out[(size_t)b * COUT + lane + u * 64] = (float)cnt[u];
}

// ---------------------------------------------------------------------------
extern "C" void kernel_launch(void* const* d_in, const int* in_sizes, int n_in,
                              void* d_out, int out_size, void* d_ws, size_t ws_size,
                              hipStream_t stream) {
    const float* x  = (const float*)d_in[0];
    const float* W  = (const float*)d_in[1];
    const int*   tw = (const int*)d_in[2];
    float* out = (float*)d_out;

    int8_t* Ai = (int8_t*)d_ws;                                   // 33,554,432 B
    int8_t* Bd = Ai + (size_t)B_DIM * CIN;                        // 12,582,912 B
    int*    S  = (int*)(Bd + (size_t)NPLN * CIN);                 // 100,663,296 B
    unsigned long long* cm =
        (unsigned long long*)((int8_t*)S + (size_t)B_DIM * NPLN * 4);  // 8,192 B

    hipLaunchKernelGGL(prep_x,   dim3(8192),  dim3(256), 0, stream, x, Ai);
    hipLaunchKernelGGL(prep_w,   dim3(4096),  dim3(256), 0, stream, W, Bd, cm);
    hipLaunchKernelGGL(gemm_i8,  dim3(384),   dim3(512), 0, stream, Ai, Bd, S);
    hipLaunchKernelGGL(colmax_k, dim3(4, 64), dim3(256), 0, stream, S, cm);
    hipLaunchKernelGGL(scan_k,   dim3(2048),  dim3(256), 0, stream, S, cm, tw, out);
}

// Round 2
// 345.489 us; speedup vs baseline: 1.1336x; 1.0901x over previous
//
#include <hip/hip_runtime.h>
#include <cstdint>

// Problem constants (fixed instance: B=8192, Cin=4096, Cout=1024, T=10)
#define B_DIM 8192
#define CIN   4096
#define COUT  1024

// Fixed-point quantization of W: 23-bit minus headroom so top balanced digit <= 127.
constexpr double W_SCALE   = 83230720.0;        // (2^23 - 2^16) / 0.1
constexpr int    QMAX      = 8323072;           // 2^23 - 2^16
constexpr double INV_SCALE = 0.1 / 8323072.0;   // 1 / W_SCALE

using i32x4 = __attribute__((ext_vector_type(4))) int;

// ---- async global->LDS, 16B per lane. LDS dest is wave-uniform base + lane*16.
__device__ __forceinline__ void async_copy16(void* lds, const void* g) {
    auto l = (__attribute__((address_space(3))) void*)(uintptr_t)(lds);
    auto p = (const __attribute__((address_space(1))) void*)(uintptr_t)(g);
    __builtin_amdgcn_global_load_lds(p, l, 16, 0, 0);
}

// ---------------------------------------------------------------------------
// Kernel 1: x (fp32 0/1) -> i8. 16 elements per thread.
__global__ void prep_x(const float* __restrict__ x, int8_t* __restrict__ Ai) {
    const int idx = blockIdx.x * 256 + threadIdx.x;      // 2,097,152 threads
    const float4* xp = (const float4*)x + (size_t)idx * 4;
    float4 v0 = xp[0], v1 = xp[1], v2 = xp[2], v3 = xp[3];
    auto pk = [](float a, float b, float c, float d) -> int {
        return (a != 0.f ? 1 : 0) | ((b != 0.f ? 1 : 0) << 8) |
               ((c != 0.f ? 1 : 0) << 16) | ((d != 0.f ? 1 : 0) << 24);
    };
    int4 r;
    r.x = pk(v0.x, v0.y, v0.z, v0.w);
    r.y = pk(v1.x, v1.y, v1.z, v1.w);
    r.z = pk(v2.x, v2.y, v2.z, v2.w);
    r.w = pk(v3.x, v3.y, v3.z, v3.w);
    ((int4*)Ai)[idx] = r;
}

// ---------------------------------------------------------------------------
// Kernel 2: W (fp32) -> 3 balanced base-256 digit planes (i8), stacked N-major.
__global__ void prep_w(const float* __restrict__ W, int8_t* __restrict__ Bd,
                       unsigned long long* __restrict__ cm) {
    const int idx = blockIdx.x * 256 + threadIdx.x;      // 1,048,576 threads, 4 elems each
    float4 w = ((const float4*)W)[idx];
    float ws[4] = {w.x, w.y, w.z, w.w};
    char dg[3][4];
#pragma unroll
    for (int k = 0; k < 4; ++k) {
        int qv = __double2int_rn((double)ws[k] * W_SCALE);
        qv = max(0, min(QMAX, qv));
        int d0 = ((qv + 128) & 255) - 128; int tq = (qv - d0) >> 8;
        int d1 = ((tq + 128) & 255) - 128; int d2 = (tq - d1) >> 8;   // d2 in [0,127]
        dg[0][k] = (char)d0; dg[1][k] = (char)d1; dg[2][k] = (char)d2;
    }
    const size_t off = (size_t)idx * 4;  // = j*4096 + c (no row crossing: 4096 % 4 == 0)
#pragma unroll
    for (int p = 0; p < 3; ++p) {
        char4 c4; c4.x = dg[p][0]; c4.y = dg[p][1]; c4.z = dg[p][2]; c4.w = dg[p][3];
        *(char4*)(Bd + (size_t)p * COUT * CIN + off) = c4;
    }
    if (idx < COUT) cm[idx] = 0ull;
}

// ---------------------------------------------------------------------------
// Kernel 3: plane-fused i8 GEMM + fp64 combine + in-block column max.
//   Tile: 128 rows x 256 combined output columns; all 3 digit planes per block.
//   Grid 64x4 = 256 blocks = exactly one dispatch round (1 block/CU).
//   8 waves (2M x 4N), per wave 64x64 per plane; acc = 3 x 16 i32x4 (192 regs).
//   Per K-tile (BK=128): 6 phases (kk-outer, plane-inner), 16 MFMA each.
//   A-frags reused across planes. Counted vmcnt (6/2/-/-/-/4), raw s_barrier,
//   2-barrier stage/read separation, both-sides chunk^(row&7) swizzle.
//   LDS: A 2x16K dbuf | B 3x32K (buf = plane, restaged each tile) = 131072 B.
//   Epilogue: isum = s0 + 256*s1 + 65536*s2 (exact i64), v = (double)isum *
//   INV_SCALE -> Sc (fp64), and per-column max -> cm via atomicMax (colmax_k
//   is gone; bit-identical numerics to the old colmax/scan path).
template <int P>
__device__ __forceinline__ void mma16(const i32x4 (&a)[4], const i32x4 (&b)[4],
                                      i32x4 (&acc)[3][4][4]) {
    __builtin_amdgcn_s_setprio(1);
#pragma unroll
    for (int mi = 0; mi < 4; ++mi)
#pragma unroll
        for (int ni = 0; ni < 4; ++ni)
            acc[P][mi][ni] = __builtin_amdgcn_mfma_i32_16x16x64_i8(
                a[mi], b[ni], acc[P][mi][ni], 0, 0, 0);
    __builtin_amdgcn_s_setprio(0);
}

#define BAR()   __builtin_amdgcn_s_barrier()
#define LGKM0() asm volatile("s_waitcnt lgkmcnt(0)" ::: "memory")
#define VMW(n)  asm volatile("s_waitcnt vmcnt(" #n ")" ::: "memory")

__global__ __launch_bounds__(512, 2) void gemm_i8(const int8_t* __restrict__ A,
                                                  const int8_t* __restrict__ Bm,
                                                  double* __restrict__ Sc,
                                                  unsigned long long* __restrict__ cm) {
    // [0,32768) = A dbuf (2 x 128 x 128B); [32768,131072) = B bufs (plane p at
    // 32768 + p*32768, 256 x 128B each)
    __shared__ alignas(16) int8_t lds[131072];
    const int tid  = threadIdx.x;
    const int lane = tid & 63;
    const int wave = tid >> 6;

    // XCD mapping: round-robin dispatch puts wg -> XCD wg&7, so bn = wg&3 is
    // XCD-stable (each XCD's 1.5 MB B-slice stays L2-resident); bm = wg>>2
    // advances in near-lockstep across XCDs -> A tiles hit LLC.
    const int wg = (int)blockIdx.x;
    const int bn = wg & 3;           // 0..3   (256 combined columns each)
    const int bm = wg >> 2;          // 0..63  (128 rows each)

    // staging: thread t owns LDS slot (row tid>>3, chunk tid&3 of 8), fetches
    // pre-swizzled global chunk (tid&7) ^ (row&7).
    const int stid   = tid >> 3;                            // 0..63
    const int cswz16 = ((tid & 7) ^ (stid & 7)) << 4;
    const int8_t* gA = A  + (size_t)(bm * 128 + stid) * CIN + cswz16;
    const int8_t* gB = Bm + (size_t)(bn * 256 + stid) * CIN + cswz16;
    const int wv1024 = wave << 10;

#define SA_(t_) do {                                                            \
    int8_t* d_ = lds + (((t_) & 1) << 14) + wv1024;                             \
    const int8_t* s_ = gA + ((t_) << 7);                                        \
    async_copy16(d_,        s_);                                                \
    async_copy16(d_ + 8192, s_ + (size_t)64 * CIN);                             \
} while (0)
#define SB_(t_, p_) do {                                                        \
    int8_t* d_ = lds + 32768 + ((p_) << 15) + wv1024;                           \
    const int8_t* s_ = gB + (size_t)(p_) * COUT * CIN + ((t_) << 7);            \
    async_copy16(d_,         s_);                                               \
    async_copy16(d_ + 8192,  s_ + (size_t)64  * CIN);                           \
    async_copy16(d_ + 16384, s_ + (size_t)128 * CIN);                           \
    async_copy16(d_ + 24576, s_ + (size_t)192 * CIN);                           \
} while (0)

    // fragment addressing (16x16x64: lane holds [m=lane&15][16B at k-chunk q])
    const int wr = wave >> 2, wc = wave & 3;
    const int fr = lane & 15;
    const int q  = lane >> 4;
    const int ck0 = (q ^ (fr & 7)) << 4;        // swizzled chunk, kk0; kk1 = ^64
    const int abase = (wr * 64 + fr) * 128;     // + mi*2048 + Abuf*16384
    const int bbase = (wc * 64 + fr) * 128;     // + ni*2048 + 32768 + p*32768

    i32x4 a[4], b[4];
    i32x4 acc[3][4][4] = {};

#define LDA_(t_, kk_) do {                                                      \
    const int8_t* p_ = lds + (((t_) & 1) << 14) + abase + (ck0 ^ ((kk_) * 64)); \
    a[0] = *(const i32x4*)(p_);        a[1] = *(const i32x4*)(p_ + 2048);       \
    a[2] = *(const i32x4*)(p_ + 4096); a[3] = *(const i32x4*)(p_ + 6144);       \
} while (0)
#define LDB_(p_, kk_) do {                                                      \
    const int8_t* q_ = lds + 32768 + ((p_) << 15) + bbase + (ck0 ^ ((kk_) * 64)); \
    b[0] = *(const i32x4*)(q_);        b[1] = *(const i32x4*)(q_ + 2048);       \
    b[2] = *(const i32x4*)(q_ + 4096); b[3] = *(const i32x4*)(q_ + 6144);       \
} while (0)

    // prologue: A(0), Bp0(0), Bp1(0) issued (10 loads); need first 6 landed.
    SA_(0); SB_(0, 0); SB_(0, 1);
    VMW(4); BAR();

#pragma unroll 1
    for (int t = 0; t < 31; ++t) {
        // P0 (kk0,p0): stage Bp2(t) then A(t+1)  [ledger: VMW(6) protects Bp1(t)]
        LDA_(t, 0); LDB_(0, 0); SB_(t, 2); SA_(t + 1);
        BAR(); LGKM0(); mma16<0>(a, b, acc); VMW(6); BAR();
        // P1 (kk0,p1)                           [VMW(2) protects Bp2(t)]
        LDB_(1, 0);
        BAR(); LGKM0(); mma16<1>(a, b, acc); VMW(2); BAR();
        // P2 (kk0,p2)
        LDB_(2, 0);
        BAR(); LGKM0(); mma16<2>(a, b, acc); BAR();
        // P3 (kk1,p0): last read of Bp0(t) / A(t)
        LDA_(t, 1); LDB_(0, 1);
        BAR(); LGKM0(); mma16<0>(a, b, acc); BAR();
        // P4 (kk1,p1): Bp0(t+1) may now overwrite buf0 (2 barriers past P3 reads)
        LDB_(1, 1); SB_(t + 1, 0);
        BAR(); LGKM0(); mma16<1>(a, b, acc); BAR();
        // P5 (kk1,p2): Bp1(t+1) overwrites buf1  [VMW(4) protects A(t+1),Bp0(t+1)]
        LDB_(2, 1); SB_(t + 1, 1);
        BAR(); LGKM0(); mma16<2>(a, b, acc); VMW(4); BAR();
    }
    // tail: t = 31 (no A(32)/Bp0(32)/Bp1(32); waits relax 4 -> 0)
    LDA_(31, 0); LDB_(0, 0); SB_(31, 2);
    BAR(); LGKM0(); mma16<0>(a, b, acc); VMW(4); BAR();
    LDB_(1, 0);
    BAR(); LGKM0(); mma16<1>(a, b, acc); VMW(0); BAR();
    LDB_(2, 0);
    BAR(); LGKM0(); mma16<2>(a, b, acc); BAR();
    LDA_(31, 1); LDB_(0, 1);
    BAR(); LGKM0(); mma16<0>(a, b, acc); BAR();
    LDB_(1, 1);
    BAR(); LGKM0(); mma16<1>(a, b, acc); BAR();
    LDB_(2, 1);
    BAR(); LGKM0(); mma16<2>(a, b, acc); BAR();

    // ---- epilogue: exact fp64 combine + store + in-block column max ----
    // C/D layout: col = lane&15 (N, from b), row = (lane>>4)*4 + reg (M, from a)
    const int gm0 = bm * 128 + wr * 64 + q * 4;
    const int gn0 = bn * 256 + wc * 64 + fr;
    double vmax[4] = {0.0, 0.0, 0.0, 0.0};
#pragma unroll
    for (int mi = 0; mi < 4; ++mi)
#pragma unroll
        for (int ni = 0; ni < 4; ++ni) {
            const int gn = gn0 + ni * 16;
#pragma unroll
            for (int reg = 0; reg < 4; ++reg) {
                const int gm = gm0 + mi * 16 + reg;
                long long isum = (long long)acc[0][mi][ni][reg]
                               + 256ll   * (long long)acc[1][mi][ni][reg]
                               + 65536ll * (long long)acc[2][mi][ni][reg];
                double v = (double)isum * INV_SCALE;   // bit-identical to old path
                Sc[(size_t)gm * COUT + gn] = v;
                vmax[ni] = fmax(vmax[ni], v);
            }
        }
    // reduce over the 4 q-groups (same columns) within the wave
#pragma unroll
    for (int ni = 0; ni < 4; ++ni) {
        vmax[ni] = fmax(vmax[ni], __shfl_xor(vmax[ni], 16, 64));
        vmax[ni] = fmax(vmax[ni], __shfl_xor(vmax[ni], 32, 64));
    }
    double* red = (double*)lds;      // safe: all LDS reads done (final BAR above)
    if (lane < 16) {
#pragma unroll
        for (int ni = 0; ni < 4; ++ni)
            red[wave * 64 + ni * 16 + fr] = vmax[ni];
    }
    __syncthreads();
    if (tid < 256) {
        const int c = tid;                       // column within block: wc*64+ni*16+fr
        const int wcq = c >> 6, nic = (c >> 4) & 3, frc = c & 15;
        double m = fmax(red[wcq * 64 + nic * 16 + frc],
                        red[(wcq + 4) * 64 + nic * 16 + frc]);
        atomicMax(cm + bn * 256 + c, (unsigned long long)__double_as_longlong(m));
    }
#undef SA_
#undef SB_
#undef LDA_
#undef LDB_
}

// ---------------------------------------------------------------------------
// Kernel 4: LIF/WTA scan, one wave per batch row, 16 fp64 neurons per lane.
__global__ void scan_k(const double* __restrict__ Sc, const unsigned long long* __restrict__ cm,
                       const int* __restrict__ twp, float* __restrict__ out) {
    const int lane = threadIdx.x & 63;
    const int wave = threadIdx.x >> 6;
    const int b = blockIdx.x * 4 + wave;
    const int T = *twp;
    const double* row = Sc + (size_t)b * COUT;

    double iv[16], mem[16], thr[16];
    int cnt[16];
    double imax = 0.0;
#pragma unroll
    for (int u = 0; u < 16; ++u) {
        const int j = lane + u * 64;
        iv[u]  = row[j];
        thr[u] = 3.0 * __longlong_as_double((long long)cm[j]);
        mem[u] = 0.0; cnt[u] = 0;
        imax = fmax(imax, iv[u]);
    }
#pragma unroll
    for (int d = 32; d >= 1; d >>= 1) imax = fmax(imax, __shfl_xor(imax, d, 64));
    const double h = 1.625 * imax;   // INH * imax

    for (int t = 0; t < T; ++t) {
        int first = 0x7fffffff;
        bool sp[16];
#pragma unroll
        for (int u = 0; u < 16; ++u) {
            mem[u] = mem[u] * 0.99 + iv[u];
            sp[u] = mem[u] > thr[u];
            if (sp[u]) first = min(first, lane + u * 64);
        }
#pragma unroll
        for (int d = 32; d >= 1; d >>= 1) first = min(first, __shfl_xor(first, d, 64));
        const bool rowspike = first < 0x7fffffff;
#pragma unroll
        for (int u = 0; u < 16; ++u) {
            if (sp[u]) mem[u] = 0.0;
            if (rowspike) {
                if (lane + u * 64 == first) cnt[u]++;
                else mem[u] -= h;
            }
        }
    }
#pragma unroll
    for (int u = 0; u < 16; ++u)
        out[(size_t)b * COUT + lane + u * 64] = (float)cnt[u];
}

// ---------------------------------------------------------------------------
extern "C" void kernel_launch(void* const* d_in, const int* in_sizes, int n_in,
                              void* d_out, int out_size, void* d_ws, size_t ws_size,
                              hipStream_t stream) {
    const float* x  = (const float*)d_in[0];
    const float* W  = (const float*)d_in[1];
    const int*   tw = (const int*)d_in[2];
    float* out = (float*)d_out;

    int8_t* Ai = (int8_t*)d_ws;                                   // 33,554,432 B
    int8_t* Bd = Ai + (size_t)B_DIM * CIN;                        // 12,582,912 B
    double* Sc = (double*)(Bd + (size_t)3 * COUT * CIN);          // 67,108,864 B
    unsigned long long* cm =
        (unsigned long long*)((int8_t*)Sc + (size_t)B_DIM * COUT * 8);  // 8,192 B

    hipLaunchKernelGGL(prep_x,  dim3(8192), dim3(256), 0, stream, x, Ai);
    hipLaunchKernelGGL(prep_w,  dim3(4096), dim3(256), 0, stream, W, Bd, cm);
    hipLaunchKernelGGL(gemm_i8, dim3(256),  dim3(512), 0, stream, Ai, Bd, Sc, cm);
    hipLaunchKernelGGL(scan_k,  dim3(2048), dim3(256), 0, stream, Sc, cm, tw, out);
}